// Round 19
// baseline (386.911 us; speedup 1.0000x reference)
//
#include <hip/hip_runtime.h>
#include <stdint.h>

typedef unsigned short u16;
typedef _Float16 f16;
typedef __attribute__((ext_vector_type(8))) _Float16 f16x8;
typedef __attribute__((ext_vector_type(4))) float f32x4;

#define DA 768
#define DT 512
#define NV 49408
#define MTOT 2048
#define NB_N 193          // n-blocks for k_score (256-wide tiles)
#define KS 16             // k_pv K-split (slices of 97/96 BK32-tiles)

__device__ __forceinline__ u16 f2h(float f) {
  return __builtin_bit_cast(u16, (f16)f);
}
__device__ __forceinline__ float h2f(u16 u) {
  return (float)__builtin_bit_cast(f16, u);
}

__device__ __forceinline__ void gload16(const void* g, void* l) {
  __builtin_amdgcn_global_load_lds((const __attribute__((address_space(1))) void*)g,
                                   (__attribute__((address_space(3))) void*)l,
                                   16, 0, 0);
}
#define SBAR()   __builtin_amdgcn_s_barrier()
#define SCHED0() __builtin_amdgcn_sched_barrier(0)
#define MFMA16(a, b, c) __builtin_amdgcn_mfma_f32_16x16x32_f16((a), (b), (c), 0, 0, 0)

// ---------------- audio -> f16 -------------------------------------------
__global__ __launch_bounds__(256) void k_a2h(const float* __restrict__ a,
                                             u16* __restrict__ ah) {
  int i = (blockIdx.x * 256 + threadIdx.x) * 8;
  float4 x = *(const float4*)&a[i];
  float4 y = *(const float4*)&a[i + 4];
  union { u16 u[8]; int4 q; } pk;
  pk.u[0] = f2h(x.x); pk.u[1] = f2h(x.y); pk.u[2] = f2h(x.z); pk.u[3] = f2h(x.w);
  pk.u[4] = f2h(y.x); pk.u[5] = f2h(y.y); pk.u[6] = f2h(y.z); pk.u[7] = f2h(y.w);
  *(int4*)&ah[i] = pk.q;
}

// ---------------- W[768][512] -> WT[512][768] f16 -------------------------
__global__ __launch_bounds__(256) void k_wT(const float* __restrict__ W,
                                            u16* __restrict__ WT) {
  __shared__ float tile[64][65];
  const int k0 = blockIdx.y * 64, n0 = blockIdx.x * 64;
  const int t = threadIdx.x;
  const int r = t >> 4, c4 = (t & 15) * 4;
#pragma unroll
  for (int i = 0; i < 4; ++i) {
    float4 x = *(const float4*)&W[(size_t)(k0 + r + i * 16) * DT + n0 + c4];
    tile[r + i * 16][c4 + 0] = x.x; tile[r + i * 16][c4 + 1] = x.y;
    tile[r + i * 16][c4 + 2] = x.z; tile[r + i * 16][c4 + 3] = x.w;
  }
  __syncthreads();
  const int nr = t >> 2, kc = (t & 3) * 16;
  union { u16 u[8]; int4 q; } p0, p1;
#pragma unroll
  for (int i = 0; i < 8; ++i) p0.u[i] = f2h(tile[kc + i][nr]);
#pragma unroll
  for (int i = 0; i < 8; ++i) p1.u[i] = f2h(tile[kc + 8 + i][nr]);
  u16* dst = WT + (size_t)(n0 + nr) * DA + k0 + kc;
  *(int4*)dst = p0.q;
  *(int4*)(dst + 8) = p1.q;
}

// ---------------- stats reduce: 16 m-blocks -> column sum/sumsq ----------
__global__ __launch_bounds__(256) void k_stats2(const float* __restrict__ pstat,
                                                float* __restrict__ stats) {
  int c = blockIdx.x * 256 + threadIdx.x;   // 0..511
  float s = 0.f, q = 0.f;
#pragma unroll
  for (int b = 0; b < 16; ++b) {
    s += pstat[(size_t)b * 512 + c];
    q += pstat[8192 + (size_t)b * 512 + c];
  }
  stats[c] = s;
  stats[DT + c] = q;
}

// ---------------- BN apply + row L2 normalize -> f16 ---------------------
__global__ __launch_bounds__(64) void k_bnnorm(const float* __restrict__ P,
                                               const float* __restrict__ stats,
                                               const float* __restrict__ gamma,
                                               const float* __restrict__ beta,
                                               u16* __restrict__ bnn) {
  const int r = blockIdx.x, l = threadIdx.x;
  float v[8];
  float ss = 0.f;
#pragma unroll
  for (int i = 0; i < 8; ++i) {
    int c = l * 8 + i;
    float mean = stats[c] * (1.f / MTOT);
    float var = stats[DT + c] * (1.f / MTOT) - mean * mean;
    float is = rsqrtf(var + 1e-5f);
    float x = (P[(size_t)r * DT + c] - mean) * is * gamma[c] + beta[c];
    v[i] = x; ss += x * x;
  }
#pragma unroll
  for (int off = 32; off > 0; off >>= 1) ss += __shfl_xor(ss, off);
  float rn = rsqrtf(ss);
  union { u16 u[8]; int4 q; } pk;
#pragma unroll
  for (int i = 0; i < 8; ++i) pk.u[i] = f2h(v[i] * rn);
  *(int4*)&bnn[(size_t)r * DT + l * 8] = pk.q;
}

// ------- fused emb prep: one pass -> embH (f16), embT (f16), invn --------
__global__ __launch_bounds__(256) void k_embprep2(const float* __restrict__ emb,
                                                  u16* __restrict__ embH,
                                                  u16* __restrict__ embT,
                                                  float* __restrict__ invn) {
  __shared__ float tile[64][65];
  const int v0 = blockIdx.x * 64;
  const int t = threadIdx.x;
  const int r = t >> 4, c4 = (t & 15) * 4;
  const int vr = t >> 2, hc = (t & 3) * 16;
  const int dr = t >> 2, vc = (t & 3) * 16;
  float ssq = 0.f;
  for (int d0 = 0; d0 < DT; d0 += 64) {
    __syncthreads();
#pragma unroll
    for (int i = 0; i < 4; ++i) {
      float4 x = *(const float4*)&emb[(size_t)(v0 + r + i * 16) * DT + d0 + c4];
      tile[r + i * 16][c4 + 0] = x.x; tile[r + i * 16][c4 + 1] = x.y;
      tile[r + i * 16][c4 + 2] = x.z; tile[r + i * 16][c4 + 3] = x.w;
    }
    __syncthreads();
    union { u16 u[8]; int4 q; } pa, pb;
#pragma unroll
    for (int i = 0; i < 8; ++i) { float f = tile[vr][hc + i];     pa.u[i] = f2h(f); ssq += f * f; }
#pragma unroll
    for (int i = 0; i < 8; ++i) { float f = tile[vr][hc + 8 + i]; pb.u[i] = f2h(f); ssq += f * f; }
    *(int4*)&embH[(size_t)(v0 + vr) * DT + d0 + hc] = pa.q;
    *(int4*)&embH[(size_t)(v0 + vr) * DT + d0 + hc + 8] = pb.q;
    union { u16 u[8]; int4 q; } p0, p1;
#pragma unroll
    for (int i = 0; i < 8; ++i) p0.u[i] = f2h(tile[vc + i][dr]);
#pragma unroll
    for (int i = 0; i < 8; ++i) p1.u[i] = f2h(tile[vc + 8 + i][dr]);
    u16* dst = embT + (size_t)(d0 + dr) * NV + v0 + vc;
    *(int4*)dst = p0.q;
    *(int4*)(dst + 8) = p1.q;
  }
  ssq += __shfl_xor(ssq, 1);
  ssq += __shfl_xor(ssq, 2);
  if ((t & 3) == 0) invn[v0 + vr] = rsqrtf(ssq) * 10.0f;
}

// ======== 512-thread 128x256 BK=32 K-loop (proven: VGPR 64, 2 blk/CU) ====
__device__ __forceinline__ void kloop256(const f16* __restrict__ A,
                                         const f16* __restrict__ B,
                                         int lda, int ldb, size_t kb, int NT,
                                         int m0, int n0, int tid,
                                         f16* ldsA, f16* ldsB,
                                         f32x4 (&acc)[4][4]) {
  const int l = tid & 63, lr = l & 15, lg = l >> 4;
  const int w = tid >> 6, wm = w >> 2, wn = w & 3;
  const int rA = tid >> 2, qA = tid & 3;
  const int qsA = qA ^ ((rA >> 1) & 3);
  const f16* gA = A + (size_t)(m0 + rA) * lda + kb + qsA * 8;
  const f16* gB0;
  const f16* gB1;
  { int r = tid >> 2, q = tid & 3; int qs = q ^ ((r >> 1) & 3);
    gB0 = B + (size_t)(n0 + r) * ldb + kb + qs * 8; }
  { int c = tid + 512; int r = c >> 2, q = c & 3; int qs = q ^ ((r >> 1) & 3);
    gB1 = B + (size_t)(n0 + r) * ldb + kb + qs * 8; }
  auto STAGE = [&](int buf, int k0) {
    gload16(gA + k0, (void*)&ldsA[(size_t)buf * 4096 + (size_t)tid * 8]);
    gload16(gB0 + k0, (void*)&ldsB[(size_t)buf * 8192 + (size_t)tid * 8]);
    gload16(gB1 + k0, (void*)&ldsB[(size_t)buf * 8192 + (size_t)(tid + 512) * 8]);
  };
  const int gsw = lg ^ ((lr >> 1) & 3);

  STAGE(0, 0);
  STAGE(1, 32);
  asm volatile("s_waitcnt vmcnt(3)" ::: "memory"); SCHED0();
  SBAR(); SCHED0();
  int cur = 0;
  for (int it = 0; it < NT; ++it) {
    const f16* bufA = ldsA + cur * 4096;
    const f16* bufB = ldsB + cur * 8192;
    f16x8 af[4], bf[4];
#pragma unroll
    for (int i = 0; i < 4; ++i)
      af[i] = *(const f16x8*)&bufA[(wm * 64 + i * 16 + lr) * 32 + gsw * 8];
#pragma unroll
    for (int j = 0; j < 4; ++j)
      bf[j] = *(const f16x8*)&bufB[(wn * 64 + j * 16 + lr) * 32 + gsw * 8];
#pragma unroll
    for (int i = 0; i < 4; ++i)
#pragma unroll
      for (int j = 0; j < 4; ++j)
        acc[i][j] = MFMA16(af[i], bf[j], acc[i][j]);
    asm volatile("s_waitcnt lgkmcnt(0)" ::: "memory"); SCHED0();
    SBAR(); SCHED0();
    if (it + 2 < NT) {
      STAGE(cur, (it + 2) * 32);
      asm volatile("s_waitcnt vmcnt(3)" ::: "memory");
    } else {
      asm volatile("s_waitcnt vmcnt(0)" ::: "memory");
    }
    SCHED0();
    SBAR(); SCHED0();
    cur ^= 1;
  }
}

// ---------------- k_proj: proj = audioH @ WT^T + bias + BN psums ---------
__global__ __launch_bounds__(512) void k_proj(const f16* __restrict__ A,
                                              const f16* __restrict__ Bt,
                                              const float* __restrict__ bias,
                                              float* __restrict__ P,
                                              float* __restrict__ pstat) {
  __shared__ f16 sm[24576];
  const int t = threadIdx.x;
  const int l = t & 63, lr = l & 15, lg = l >> 4;
  const int w = t >> 6, wm = w >> 2, wn = w & 3;
  const int m0 = blockIdx.x * 128;
  const int n0 = blockIdx.y * 256;

  f32x4 acc[4][4];
#pragma unroll
  for (int i = 0; i < 4; ++i)
#pragma unroll
    for (int j = 0; j < 4; ++j) acc[i][j] = (f32x4){0.f, 0.f, 0.f, 0.f};

  kloop256(A, Bt, DA, DA, 0, DA / 32, m0, n0, t, sm, sm + 8192, acc);

  float ssum[4] = {0.f, 0.f, 0.f, 0.f}, sq[4] = {0.f, 0.f, 0.f, 0.f};
#pragma unroll
  for (int j = 0; j < 4; ++j) {
    int col = n0 + wn * 64 + j * 16 + lr;
    float bj = bias[col];
#pragma unroll
    for (int i = 0; i < 4; ++i)
#pragma unroll
      for (int rg = 0; rg < 4; ++rg) {
        int row = m0 + wm * 64 + i * 16 + lg * 4 + rg;
        float e = acc[i][j][rg] + bj;
        P[(size_t)row * DT + col] = e;
        ssum[j] += e; sq[j] += e * e;
      }
  }
#pragma unroll
  for (int m = 16; m <= 32; m <<= 1)
#pragma unroll
    for (int j = 0; j < 4; ++j) {
      ssum[j] += __shfl_xor(ssum[j], m);
      sq[j]   += __shfl_xor(sq[j], m);
    }
  float* psA = (float*)sm;        // [2 wm][256 cols]
  float* psQ = (float*)sm + 512;
  if (lg == 0) {
#pragma unroll
    for (int j = 0; j < 4; ++j) {
      psA[wm * 256 + wn * 64 + j * 16 + lr] = ssum[j];
      psQ[wm * 256 + wn * 64 + j * 16 + lr] = sq[j];
    }
  }
  __syncthreads();
  if (t < 256) {
    pstat[(size_t)blockIdx.x * 512 + n0 + t] = psA[t] + psA[256 + t];
    pstat[8192 + (size_t)blockIdx.x * 512 + n0 + t] = psQ[t] + psQ[256 + t];
  }
}

// ---------------- k_score: E = exp(invn * (bnnH @ embH^T)) ---------------
__global__ __launch_bounds__(512) void k_score(const f16* __restrict__ A,
                                               const f16* __restrict__ Bt,
                                               const float* __restrict__ invn,
                                               u16* __restrict__ E,
                                               float* __restrict__ lpart,
                                               int row0, int CH) {
  __shared__ f16 sm[24576];
  __shared__ float psum[512];
  const int t = threadIdx.x;
  const int l = t & 63, lr = l & 15, lg = l >> 4;
  const int w = t >> 6, wm = w >> 2, wn = w & 3;
  const int mB = CH >> 7;
  const int nwg = NB_N * mB;
  const int o = blockIdx.x + blockIdx.y * NB_N;
  const int v = (o & 7) * (nwg >> 3) + (o >> 3);     // bijective XCD chunking
  const int nb = v / mB, by = v % mB;
  const int n0 = nb * 256;
  const int mloc = by * 128;
  const int m0 = row0 + mloc;

  f32x4 acc[4][4];
#pragma unroll
  for (int i = 0; i < 4; ++i)
#pragma unroll
    for (int j = 0; j < 4; ++j) acc[i][j] = (f32x4){0.f, 0.f, 0.f, 0.f};

  kloop256(A, Bt, DT, DT, 0, DT / 32, m0, n0, t, sm, sm + 8192, acc);

  // ---- epilogue: exp + per-half bounce (waves wm==r2 own half r2) ------
  float inv_j[4];
#pragma unroll
  for (int j = 0; j < 4; ++j) inv_j[j] = invn[n0 + wn * 64 + j * 16 + lr];
  float rs[4][4] = {};
#pragma unroll
  for (int r2 = 0; r2 < 2; ++r2) {
    if (wm == r2) {
#pragma unroll
      for (int i = 0; i < 4; ++i)
#pragma unroll
        for (int j = 0; j < 4; ++j)
#pragma unroll
          for (int rg = 0; rg < 4; ++rg) {
            float e = __expf(acc[i][j][rg] * inv_j[j]);
            rs[i][rg] += e;
            int lrow = i * 16 + lg * 4 + rg;             // 0..63
            sm[lrow * 256 + wn * 64 + j * 16 + lr] = (f16)e;
          }
    }
    __syncthreads();
#pragma unroll
    for (int cc = 0; cc < 4; ++cc) {
      int chunk = t + cc * 512;                          // 0..2047
      int row = chunk >> 5, g = chunk & 31;
      *(int4*)&E[(size_t)(mloc + r2 * 64 + row) * NV + n0 + g * 8] =
          *(const int4*)&sm[chunk * 8];
    }
    __syncthreads();
  }
  // ---- row sums: reduce over lr, combine 4 n-waves via psum ------------
#pragma unroll
  for (int m = 1; m <= 8; m <<= 1)
#pragma unroll
    for (int i = 0; i < 4; ++i)
#pragma unroll
      for (int rg = 0; rg < 4; ++rg) rs[i][rg] += __shfl_xor(rs[i][rg], m);
  if (lr == 0) {
#pragma unroll
    for (int i = 0; i < 4; ++i)
#pragma unroll
      for (int rg = 0; rg < 4; ++rg)
        psum[(wm * 64 + i * 16 + lg * 4 + rg) * 4 + wn] = rs[i][rg];
  }
  __syncthreads();
  if (t < 128)
    lpart[(size_t)nb * CH + mloc + t] =
        psum[t * 4 + 0] + psum[t * 4 + 1] + psum[t * 4 + 2] + psum[t * 4 + 3];
}

// ---------------- k_pv: Op[z] = E @ embT^T (f16 out), 256x256 tile -------
__global__ __launch_bounds__(1024) void k_pv(const f16* __restrict__ A,
                                             const f16* __restrict__ Bt,
                                             u16* __restrict__ Op,
                                             int CH) {
  extern __shared__ char lds[];
  f16* ldsA = (f16*)lds;              // 2 x 8192 f16
  f16* ldsB = (f16*)(lds + 32768);    // 2 x 8192 f16
  const int t = threadIdx.x;
  const int l = t & 63, lr = l & 15, lg = l >> 4;
  const int w = t >> 6, wm = w >> 2, wn = w & 3;   // both 0..3
  const int mB = CH >> 8;                          // 8 m-chunks of 256
  const int nwg = 2 * mB * KS;                     // 256
  const int o = blockIdx.x + blockIdx.y * 2 + blockIdx.z * 2 * mB;
  const int v = (o & 7) * (nwg >> 3) + (o >> 3);   // bijective (nwg%8==0)
  const int n = v & 1;
  const int m = (v >> 1) % mB;
  const int z = v / (2 * mB);
  const int n0 = n * 256;
  const int m0 = m * 256;
  const int g0 = z * 96 + (z < 8 ? z : 8);         // 1544 = 8*97 + 8*96
  const int NT = 96 + (z < 8 ? 1 : 0);
  const size_t kb = (size_t)g0 * 32;

  const int rS = t >> 2, qS = t & 3;               // 256 rows x 4 granules
  const int qsS = qS ^ ((rS >> 1) & 3);            // pre-swizzled source granule
  const f16* gA = A + (size_t)(m0 + rS) * NV + kb + qsS * 8;
  const f16* gB = Bt + (size_t)(n0 + rS) * NV + kb + qsS * 8;
  auto STAGE = [&](int buf, int kt) {
    int k0 = kt * 32;
    gload16(gA + k0, (void*)&ldsA[(size_t)buf * 8192 + (size_t)t * 8]);
    gload16(gB + k0, (void*)&ldsB[(size_t)buf * 8192 + (size_t)t * 8]);
  };
  const int gsw = lg ^ ((lr >> 1) & 3);            // matching read-granule swizzle

  f32x4 acc[4][4];
#pragma unroll
  for (int i = 0; i < 4; ++i)
#pragma unroll
    for (int j = 0; j < 4; ++j) acc[i][j] = (f32x4){0.f, 0.f, 0.f, 0.f};

  STAGE(0, 0);
  STAGE(1, 1);
  asm volatile("s_waitcnt vmcnt(2)" ::: "memory"); SCHED0();
  SBAR(); SCHED0();
  int cur = 0;
  for (int it = 0; it < NT; ++it) {
    const f16* bufA = ldsA + cur * 8192;
    const f16* bufB = ldsB + cur * 8192;
    f16x8 af[4], bf[4];
#pragma unroll
    for (int i = 0; i < 4; ++i)
      af[i] = *(const f16x8*)&bufA[(wm * 64 + i * 16 + lr) * 32 + gsw * 8];
#pragma unroll
    for (int j = 0; j < 4; ++j)
      bf[j] = *(const f16x8*)&bufB[(wn * 64 + j * 16 + lr) * 32 + gsw * 8];
#pragma unroll
    for (int i = 0; i < 4; ++i)
#pragma unroll
      for (int j = 0; j < 4; ++j)
        acc[i][j] = MFMA16(af[i], bf[j], acc[i][j]);
    asm volatile("s_waitcnt lgkmcnt(0)" ::: "memory"); SCHED0();
    SBAR(); SCHED0();
    if (it + 2 < NT) {
      STAGE(cur, it + 2);
      asm volatile("s_waitcnt vmcnt(2)" ::: "memory");
    } else {
      asm volatile("s_waitcnt vmcnt(0)" ::: "memory");
    }
    SCHED0();
    SBAR(); SCHED0();
    cur ^= 1;
  }

#pragma unroll
  for (int i = 0; i < 4; ++i)
#pragma unroll
    for (int j = 0; j < 4; ++j)
#pragma unroll
      for (int rg = 0; rg < 4; ++rg) {
        int row = m0 + wm * 64 + i * 16 + lg * 4 + rg;
        int col = n0 + wn * 64 + j * 16 + lr;
        Op[((size_t)z * CH + row) * DT + col] = f2h(acc[i][j][rg]);
      }
}

// ---------------- l[r] = sum over vocab of E -----------------------------
__global__ __launch_bounds__(256) void k_lred(const float* __restrict__ lp,
                                              float* __restrict__ lv, int CH) {
  int rb = blockIdx.x * 256 + threadIdx.x;
  float s = 0.f;
  for (int nb = 0; nb < NB_N; ++nb) s += lp[(size_t)nb * CH + rb];
  lv[rb] = s;
}

// ------- combine split-K (f16 partials, int4 loads) + divide by l --------
__global__ __launch_bounds__(256) void k_out(const u16* __restrict__ Op,
                                             const float* __restrict__ lv,
                                             float* __restrict__ out,
                                             int row0, int CH) {
  int idx = blockIdx.x * 256 + threadIdx.x;
  int rb = idx >> 6, c8 = (idx & 63) * 8;
  float s[8] = {};
#pragma unroll
  for (int zz = 0; zz < KS; ++zz) {
    int4 vq = *(const int4*)&Op[((size_t)zz * CH + rb) * DT + c8];
    const f16* h = (const f16*)&vq;
#pragma unroll
    for (int k = 0; k < 8; ++k) s[k] += (float)h[k];
  }
  float inv = 1.0f / lv[rb];
  float4 o0 = {s[0] * inv, s[1] * inv, s[2] * inv, s[3] * inv};
  float4 o1 = {s[4] * inv, s[5] * inv, s[6] * inv, s[7] * inv};
  float* dst = &out[(size_t)(row0 + rb) * DT + c8];
  *(float4*)dst = o0;
  *(float4*)(dst + 4) = o1;
}

extern "C" void kernel_launch(void* const* d_in, const int* in_sizes, int n_in,
                              void* d_out, int out_size, void* d_ws, size_t ws_size,
                              hipStream_t stream) {
  const float* audio = (const float*)d_in[0];
  const float* W     = (const float*)d_in[1];
  const float* bias  = (const float*)d_in[2];
  const float* gamma = (const float*)d_in[3];
  const float* beta  = (const float*)d_in[4];
  const float* emb   = (const float*)d_in[5];
  float* out = (float*)d_out;

  char* ws = (char*)d_ws;
  size_t off = 0;
  auto alloc = [&](size_t bytes) {
    char* p = ws + off;
    off += (bytes + 255) & ~(size_t)255;
    return p;
  };
  float* proj   = (float*)alloc((size_t)MTOT * DT * 4);
  float* pstat  = (float*)alloc((size_t)2 * 16 * 512 * 4);
  float* stats  = (float*)alloc((size_t)2 * DT * 4);
  u16*   bnnH   = (u16*)alloc((size_t)MTOT * DT * 2);
  u16*   embH   = (u16*)alloc((size_t)NV * DT * 2);
  u16*   embT   = (u16*)alloc((size_t)DT * NV * 2);
  float* invn   = (float*)alloc((size_t)NV * 4);
  u16*   audioH = (u16*)alloc((size_t)MTOT * DA * 2);
  u16*   WT     = (u16*)alloc((size_t)DT * DA * 2);
  size_t fixed_off = off;

  int CH = 2048;
  while (CH > 256) {
    size_t need = fixed_off;
    need += (((size_t)CH * NV * 2) + 255) & ~(size_t)255;          // E
    need += (((size_t)NB_N * CH * 4) + 255) & ~(size_t)255;        // lpart
    need += (((size_t)CH * 4) + 255) & ~(size_t)255;               // lvec
    need += (((size_t)KS * CH * DT * 2) + 255) & ~(size_t)255;     // Op (f16)
    if (need <= ws_size) break;
    CH >>= 1;
  }
  u16*   E     = (u16*)alloc((size_t)CH * NV * 2);
  float* lpart = (float*)alloc((size_t)NB_N * CH * 4);
  float* lvec  = (float*)alloc((size_t)CH * 4);
  u16*   Op    = (u16*)alloc((size_t)KS * CH * DT * 2);
  if (ws_size < off) return;

  hipFuncSetAttribute((const void*)k_pv,
                      hipFuncAttributeMaxDynamicSharedMemorySize, 65536);

  k_a2h<<<dim3(MTOT * DA / 2048), dim3(256), 0, stream>>>(audio, audioH);
  k_wT<<<dim3(DT / 64, DA / 64), dim3(256), 0, stream>>>(W, WT);
  k_proj<<<dim3(MTOT / 128, 2), dim3(512), 0, stream>>>(
      (const f16*)audioH, (const f16*)WT, bias, proj, pstat);
  k_stats2<<<dim3(2), dim3(256), 0, stream>>>(pstat, stats);
  k_bnnorm<<<dim3(MTOT), dim3(64), 0, stream>>>(proj, stats, gamma, beta, bnnH);
  k_embprep2<<<dim3(NV / 64), dim3(256), 0, stream>>>(emb, embH, embT, invn);

  for (int row0 = 0; row0 < MTOT; row0 += CH) {
    k_score<<<dim3(NB_N, CH / 128), dim3(512), 0, stream>>>(
        (const f16*)bnnH, (const f16*)embH, invn, E, lpart, row0, CH);
    k_lred<<<dim3(CH / 256), dim3(256), 0, stream>>>(lpart, lvec, CH);
    k_pv<<<dim3(2, CH >> 8, KS), dim3(1024), 65536, stream>>>(
        (const f16*)E, (const f16*)embT, Op, CH);
    k_out<<<dim3(CH / 4), dim3(256), 0, stream>>>(Op, lvec, out, row0, CH);
  }
}

// Round 20
// 384.932 us; speedup vs baseline: 1.0051x; 1.0051x over previous
//
#include <hip/hip_runtime.h>
#include <stdint.h>

typedef unsigned short u16;
typedef _Float16 f16;
typedef __attribute__((ext_vector_type(8))) _Float16 f16x8;
typedef __attribute__((ext_vector_type(4))) float f32x4;

#define DA 768
#define DT 512
#define NV 49408
#define MTOT 2048
#define NB_N 193          // n-blocks for k_score (256-wide tiles)
#define KS 16             // k_pv K-split (slices of 97/96 BK32-tiles)

__device__ __forceinline__ u16 f2h(float f) {
  return __builtin_bit_cast(u16, (f16)f);
}
__device__ __forceinline__ float h2f(u16 u) {
  return (float)__builtin_bit_cast(f16, u);
}

__device__ __forceinline__ void gload16(const void* g, void* l) {
  __builtin_amdgcn_global_load_lds((const __attribute__((address_space(1))) void*)g,
                                   (__attribute__((address_space(3))) void*)l,
                                   16, 0, 0);
}
#define SBAR()   __builtin_amdgcn_s_barrier()
#define SCHED0() __builtin_amdgcn_sched_barrier(0)
#define MFMA16(a, b, c) __builtin_amdgcn_mfma_f32_16x16x32_f16((a), (b), (c), 0, 0, 0)

// ------- fused input prep: blocks 0..767 audio->f16, 768..863 W->WT ------
__global__ __launch_bounds__(256) void k_prep(const float* __restrict__ a,
                                              u16* __restrict__ ah,
                                              const float* __restrict__ W,
                                              u16* __restrict__ WT) {
  __shared__ float tile[64][65];
  const int b = blockIdx.x;
  const int t = threadIdx.x;
  if (b < 768) {
    int i = (b * 256 + t) * 8;
    float4 x = *(const float4*)&a[i];
    float4 y = *(const float4*)&a[i + 4];
    union { u16 u[8]; int4 q; } pk;
    pk.u[0] = f2h(x.x); pk.u[1] = f2h(x.y); pk.u[2] = f2h(x.z); pk.u[3] = f2h(x.w);
    pk.u[4] = f2h(y.x); pk.u[5] = f2h(y.y); pk.u[6] = f2h(y.z); pk.u[7] = f2h(y.w);
    *(int4*)&ah[i] = pk.q;
    return;
  }
  const int bb = b - 768;                 // 0..95
  const int n0 = (bb & 7) * 64;           // 8 n-tiles
  const int k0 = (bb >> 3) * 64;          // 12 k-tiles
  const int r = t >> 4, c4 = (t & 15) * 4;
#pragma unroll
  for (int i = 0; i < 4; ++i) {
    float4 x = *(const float4*)&W[(size_t)(k0 + r + i * 16) * DT + n0 + c4];
    tile[r + i * 16][c4 + 0] = x.x; tile[r + i * 16][c4 + 1] = x.y;
    tile[r + i * 16][c4 + 2] = x.z; tile[r + i * 16][c4 + 3] = x.w;
  }
  __syncthreads();
  const int nr = t >> 2, kc = (t & 3) * 16;
  union { u16 u[8]; int4 q; } p0, p1;
#pragma unroll
  for (int i = 0; i < 8; ++i) p0.u[i] = f2h(tile[kc + i][nr]);
#pragma unroll
  for (int i = 0; i < 8; ++i) p1.u[i] = f2h(tile[kc + 8 + i][nr]);
  u16* dst = WT + (size_t)(n0 + nr) * DA + k0 + kc;
  *(int4*)dst = p0.q;
  *(int4*)(dst + 8) = p1.q;
}

// ---------------- stats reduce: 16 m-blocks -> column sum/sumsq ----------
__global__ __launch_bounds__(256) void k_stats2(const float* __restrict__ pstat,
                                                float* __restrict__ stats) {
  int c = blockIdx.x * 256 + threadIdx.x;   // 0..511
  float s = 0.f, q = 0.f;
#pragma unroll
  for (int b = 0; b < 16; ++b) {
    s += pstat[(size_t)b * 512 + c];
    q += pstat[8192 + (size_t)b * 512 + c];
  }
  stats[c] = s;
  stats[DT + c] = q;
}

// ---------------- BN apply + row L2 normalize -> f16 ---------------------
__global__ __launch_bounds__(64) void k_bnnorm(const float* __restrict__ P,
                                               const float* __restrict__ stats,
                                               const float* __restrict__ gamma,
                                               const float* __restrict__ beta,
                                               u16* __restrict__ bnn) {
  const int r = blockIdx.x, l = threadIdx.x;
  float v[8];
  float ss = 0.f;
#pragma unroll
  for (int i = 0; i < 8; ++i) {
    int c = l * 8 + i;
    float mean = stats[c] * (1.f / MTOT);
    float var = stats[DT + c] * (1.f / MTOT) - mean * mean;
    float is = rsqrtf(var + 1e-5f);
    float x = (P[(size_t)r * DT + c] - mean) * is * gamma[c] + beta[c];
    v[i] = x; ss += x * x;
  }
#pragma unroll
  for (int off = 32; off > 0; off >>= 1) ss += __shfl_xor(ss, off);
  float rn = rsqrtf(ss);
  union { u16 u[8]; int4 q; } pk;
#pragma unroll
  for (int i = 0; i < 8; ++i) pk.u[i] = f2h(v[i] * rn);
  *(int4*)&bnn[(size_t)r * DT + l * 8] = pk.q;
}

// ------- fused emb prep: one pass -> embH (f16), embT (f16), invn --------
__global__ __launch_bounds__(256) void k_embprep2(const float* __restrict__ emb,
                                                  u16* __restrict__ embH,
                                                  u16* __restrict__ embT,
                                                  float* __restrict__ invn) {
  __shared__ float tile[64][65];
  const int v0 = blockIdx.x * 64;
  const int t = threadIdx.x;
  const int r = t >> 4, c4 = (t & 15) * 4;
  const int vr = t >> 2, hc = (t & 3) * 16;
  const int dr = t >> 2, vc = (t & 3) * 16;
  float ssq = 0.f;
  for (int d0 = 0; d0 < DT; d0 += 64) {
    __syncthreads();
#pragma unroll
    for (int i = 0; i < 4; ++i) {
      float4 x = *(const float4*)&emb[(size_t)(v0 + r + i * 16) * DT + d0 + c4];
      tile[r + i * 16][c4 + 0] = x.x; tile[r + i * 16][c4 + 1] = x.y;
      tile[r + i * 16][c4 + 2] = x.z; tile[r + i * 16][c4 + 3] = x.w;
    }
    __syncthreads();
    union { u16 u[8]; int4 q; } pa, pb;
#pragma unroll
    for (int i = 0; i < 8; ++i) { float f = tile[vr][hc + i];     pa.u[i] = f2h(f); ssq += f * f; }
#pragma unroll
    for (int i = 0; i < 8; ++i) { float f = tile[vr][hc + 8 + i]; pb.u[i] = f2h(f); ssq += f * f; }
    *(int4*)&embH[(size_t)(v0 + vr) * DT + d0 + hc] = pa.q;
    *(int4*)&embH[(size_t)(v0 + vr) * DT + d0 + hc + 8] = pb.q;
    union { u16 u[8]; int4 q; } p0, p1;
#pragma unroll
    for (int i = 0; i < 8; ++i) p0.u[i] = f2h(tile[vc + i][dr]);
#pragma unroll
    for (int i = 0; i < 8; ++i) p1.u[i] = f2h(tile[vc + 8 + i][dr]);
    u16* dst = embT + (size_t)(d0 + dr) * NV + v0 + vc;
    *(int4*)dst = p0.q;
    *(int4*)(dst + 8) = p1.q;
  }
  ssq += __shfl_xor(ssq, 1);
  ssq += __shfl_xor(ssq, 2);
  if ((t & 3) == 0) invn[v0 + vr] = rsqrtf(ssq) * 10.0f;
}

// ======== 512-thread 128x256 BK=32 K-loop (proven: VGPR 64, 2 blk/CU) ====
__device__ __forceinline__ void kloop256(const f16* __restrict__ A,
                                         const f16* __restrict__ B,
                                         int lda, int ldb, size_t kb, int NT,
                                         int m0, int n0, int tid,
                                         f16* ldsA, f16* ldsB,
                                         f32x4 (&acc)[4][4]) {
  const int l = tid & 63, lr = l & 15, lg = l >> 4;
  const int w = tid >> 6, wm = w >> 2, wn = w & 3;
  const int rA = tid >> 2, qA = tid & 3;
  const int qsA = qA ^ ((rA >> 1) & 3);
  const f16* gA = A + (size_t)(m0 + rA) * lda + kb + qsA * 8;
  const f16* gB0;
  const f16* gB1;
  { int r = tid >> 2, q = tid & 3; int qs = q ^ ((r >> 1) & 3);
    gB0 = B + (size_t)(n0 + r) * ldb + kb + qs * 8; }
  { int c = tid + 512; int r = c >> 2, q = c & 3; int qs = q ^ ((r >> 1) & 3);
    gB1 = B + (size_t)(n0 + r) * ldb + kb + qs * 8; }
  auto STAGE = [&](int buf, int k0) {
    gload16(gA + k0, (void*)&ldsA[(size_t)buf * 4096 + (size_t)tid * 8]);
    gload16(gB0 + k0, (void*)&ldsB[(size_t)buf * 8192 + (size_t)tid * 8]);
    gload16(gB1 + k0, (void*)&ldsB[(size_t)buf * 8192 + (size_t)(tid + 512) * 8]);
  };
  const int gsw = lg ^ ((lr >> 1) & 3);

  STAGE(0, 0);
  STAGE(1, 32);
  asm volatile("s_waitcnt vmcnt(3)" ::: "memory"); SCHED0();
  SBAR(); SCHED0();
  int cur = 0;
  for (int it = 0; it < NT; ++it) {
    const f16* bufA = ldsA + cur * 4096;
    const f16* bufB = ldsB + cur * 8192;
    f16x8 af[4], bf[4];
#pragma unroll
    for (int i = 0; i < 4; ++i)
      af[i] = *(const f16x8*)&bufA[(wm * 64 + i * 16 + lr) * 32 + gsw * 8];
#pragma unroll
    for (int j = 0; j < 4; ++j)
      bf[j] = *(const f16x8*)&bufB[(wn * 64 + j * 16 + lr) * 32 + gsw * 8];
#pragma unroll
    for (int i = 0; i < 4; ++i)
#pragma unroll
      for (int j = 0; j < 4; ++j)
        acc[i][j] = MFMA16(af[i], bf[j], acc[i][j]);
    asm volatile("s_waitcnt lgkmcnt(0)" ::: "memory"); SCHED0();
    SBAR(); SCHED0();
    if (it + 2 < NT) {
      STAGE(cur, (it + 2) * 32);
      asm volatile("s_waitcnt vmcnt(3)" ::: "memory");
    } else {
      asm volatile("s_waitcnt vmcnt(0)" ::: "memory");
    }
    SCHED0();
    SBAR(); SCHED0();
    cur ^= 1;
  }
}

// ---------------- k_proj: proj = audioH @ WT^T + bias + BN psums ---------
__global__ __launch_bounds__(512) void k_proj(const f16* __restrict__ A,
                                              const f16* __restrict__ Bt,
                                              const float* __restrict__ bias,
                                              float* __restrict__ P,
                                              float* __restrict__ pstat) {
  __shared__ f16 sm[24576];
  const int t = threadIdx.x;
  const int l = t & 63, lr = l & 15, lg = l >> 4;
  const int w = t >> 6, wm = w >> 2, wn = w & 3;
  const int m0 = blockIdx.x * 128;
  const int n0 = blockIdx.y * 256;

  f32x4 acc[4][4];
#pragma unroll
  for (int i = 0; i < 4; ++i)
#pragma unroll
    for (int j = 0; j < 4; ++j) acc[i][j] = (f32x4){0.f, 0.f, 0.f, 0.f};

  kloop256(A, Bt, DA, DA, 0, DA / 32, m0, n0, t, sm, sm + 8192, acc);

  float ssum[4] = {0.f, 0.f, 0.f, 0.f}, sq[4] = {0.f, 0.f, 0.f, 0.f};
#pragma unroll
  for (int j = 0; j < 4; ++j) {
    int col = n0 + wn * 64 + j * 16 + lr;
    float bj = bias[col];
#pragma unroll
    for (int i = 0; i < 4; ++i)
#pragma unroll
      for (int rg = 0; rg < 4; ++rg) {
        int row = m0 + wm * 64 + i * 16 + lg * 4 + rg;
        float e = acc[i][j][rg] + bj;
        P[(size_t)row * DT + col] = e;
        ssum[j] += e; sq[j] += e * e;
      }
  }
#pragma unroll
  for (int m = 16; m <= 32; m <<= 1)
#pragma unroll
    for (int j = 0; j < 4; ++j) {
      ssum[j] += __shfl_xor(ssum[j], m);
      sq[j]   += __shfl_xor(sq[j], m);
    }
  float* psA = (float*)sm;        // [2 wm][256 cols]
  float* psQ = (float*)sm + 512;
  if (lg == 0) {
#pragma unroll
    for (int j = 0; j < 4; ++j) {
      psA[wm * 256 + wn * 64 + j * 16 + lr] = ssum[j];
      psQ[wm * 256 + wn * 64 + j * 16 + lr] = sq[j];
    }
  }
  __syncthreads();
  if (t < 256) {
    pstat[(size_t)blockIdx.x * 512 + n0 + t] = psA[t] + psA[256 + t];
    pstat[8192 + (size_t)blockIdx.x * 512 + n0 + t] = psQ[t] + psQ[256 + t];
  }
}

// ---------------- k_score: E = exp(invn * (bnnH @ embH^T)) ---------------
__global__ __launch_bounds__(512) void k_score(const f16* __restrict__ A,
                                               const f16* __restrict__ Bt,
                                               const float* __restrict__ invn,
                                               u16* __restrict__ E,
                                               float* __restrict__ lpart,
                                               int row0, int CH) {
  __shared__ f16 sm[24576];
  __shared__ float psum[512];
  const int t = threadIdx.x;
  const int l = t & 63, lr = l & 15, lg = l >> 4;
  const int w = t >> 6, wm = w >> 2, wn = w & 3;
  const int mB = CH >> 7;
  const int nwg = NB_N * mB;
  const int o = blockIdx.x + blockIdx.y * NB_N;
  const int v = (o & 7) * (nwg >> 3) + (o >> 3);     // bijective XCD chunking
  const int nb = v / mB, by = v % mB;
  const int n0 = nb * 256;
  const int mloc = by * 128;
  const int m0 = row0 + mloc;

  f32x4 acc[4][4];
#pragma unroll
  for (int i = 0; i < 4; ++i)
#pragma unroll
    for (int j = 0; j < 4; ++j) acc[i][j] = (f32x4){0.f, 0.f, 0.f, 0.f};

  kloop256(A, Bt, DT, DT, 0, DT / 32, m0, n0, t, sm, sm + 8192, acc);

  // ---- epilogue: exp + per-half bounce (waves wm==r2 own half r2) ------
  float inv_j[4];
#pragma unroll
  for (int j = 0; j < 4; ++j) inv_j[j] = invn[n0 + wn * 64 + j * 16 + lr];
  float rs[4][4] = {};
#pragma unroll
  for (int r2 = 0; r2 < 2; ++r2) {
    if (wm == r2) {
#pragma unroll
      for (int i = 0; i < 4; ++i)
#pragma unroll
        for (int j = 0; j < 4; ++j)
#pragma unroll
          for (int rg = 0; rg < 4; ++rg) {
            float e = __expf(acc[i][j][rg] * inv_j[j]);
            rs[i][rg] += e;
            int lrow = i * 16 + lg * 4 + rg;             // 0..63
            sm[lrow * 256 + wn * 64 + j * 16 + lr] = (f16)e;
          }
    }
    __syncthreads();
#pragma unroll
    for (int cc = 0; cc < 4; ++cc) {
      int chunk = t + cc * 512;                          // 0..2047
      int row = chunk >> 5, g = chunk & 31;
      *(int4*)&E[(size_t)(mloc + r2 * 64 + row) * NV + n0 + g * 8] =
          *(const int4*)&sm[chunk * 8];
    }
    __syncthreads();
  }
  // ---- row sums: reduce over lr, combine 4 n-waves via psum ------------
#pragma unroll
  for (int m = 1; m <= 8; m <<= 1)
#pragma unroll
    for (int i = 0; i < 4; ++i)
#pragma unroll
      for (int rg = 0; rg < 4; ++rg) rs[i][rg] += __shfl_xor(rs[i][rg], m);
  if (lr == 0) {
#pragma unroll
    for (int i = 0; i < 4; ++i)
#pragma unroll
      for (int rg = 0; rg < 4; ++rg)
        psum[(wm * 64 + i * 16 + lg * 4 + rg) * 4 + wn] = rs[i][rg];
  }
  __syncthreads();
  if (t < 128)
    lpart[(size_t)nb * CH + mloc + t] =
        psum[t * 4 + 0] + psum[t * 4 + 1] + psum[t * 4 + 2] + psum[t * 4 + 3];
}

// ---------------- k_pv: Op[z] = E @ embT^T (f16 out), 256x256 tile -------
__global__ __launch_bounds__(1024) void k_pv(const f16* __restrict__ A,
                                             const f16* __restrict__ Bt,
                                             u16* __restrict__ Op,
                                             int CH) {
  extern __shared__ char lds[];
  f16* ldsA = (f16*)lds;              // 2 x 8192 f16
  f16* ldsB = (f16*)(lds + 32768);    // 2 x 8192 f16
  const int t = threadIdx.x;
  const int l = t & 63, lr = l & 15, lg = l >> 4;
  const int w = t >> 6, wm = w >> 2, wn = w & 3;   // both 0..3
  const int mB = CH >> 8;                          // 8 m-chunks of 256
  const int nwg = 2 * mB * KS;                     // 256
  const int o = blockIdx.x + blockIdx.y * 2 + blockIdx.z * 2 * mB;
  const int v = (o & 7) * (nwg >> 3) + (o >> 3);   // bijective (nwg%8==0)
  const int n = v & 1;
  const int m = (v >> 1) % mB;
  const int z = v / (2 * mB);
  const int n0 = n * 256;
  const int m0 = m * 256;
  const int g0 = z * 96 + (z < 8 ? z : 8);         // 1544 = 8*97 + 8*96
  const int NT = 96 + (z < 8 ? 1 : 0);
  const size_t kb = (size_t)g0 * 32;

  const int rS = t >> 2, qS = t & 3;               // 256 rows x 4 granules
  const int qsS = qS ^ ((rS >> 1) & 3);            // pre-swizzled source granule
  const f16* gA = A + (size_t)(m0 + rS) * NV + kb + qsS * 8;
  const f16* gB = Bt + (size_t)(n0 + rS) * NV + kb + qsS * 8;
  auto STAGE = [&](int buf, int kt) {
    int k0 = kt * 32;
    gload16(gA + k0, (void*)&ldsA[(size_t)buf * 8192 + (size_t)t * 8]);
    gload16(gB + k0, (void*)&ldsB[(size_t)buf * 8192 + (size_t)t * 8]);
  };
  const int gsw = lg ^ ((lr >> 1) & 3);            // matching read-granule swizzle

  f32x4 acc[4][4];
#pragma unroll
  for (int i = 0; i < 4; ++i)
#pragma unroll
    for (int j = 0; j < 4; ++j) acc[i][j] = (f32x4){0.f, 0.f, 0.f, 0.f};

  STAGE(0, 0);
  STAGE(1, 1);
  asm volatile("s_waitcnt vmcnt(2)" ::: "memory"); SCHED0();
  SBAR(); SCHED0();
  int cur = 0;
  for (int it = 0; it < NT; ++it) {
    const f16* bufA = ldsA + cur * 8192;
    const f16* bufB = ldsB + cur * 8192;
    f16x8 af[4], bf[4];
#pragma unroll
    for (int i = 0; i < 4; ++i)
      af[i] = *(const f16x8*)&bufA[(wm * 64 + i * 16 + lr) * 32 + gsw * 8];
#pragma unroll
    for (int j = 0; j < 4; ++j)
      bf[j] = *(const f16x8*)&bufB[(wn * 64 + j * 16 + lr) * 32 + gsw * 8];
#pragma unroll
    for (int i = 0; i < 4; ++i)
#pragma unroll
      for (int j = 0; j < 4; ++j)
        acc[i][j] = MFMA16(af[i], bf[j], acc[i][j]);
    asm volatile("s_waitcnt lgkmcnt(0)" ::: "memory"); SCHED0();
    SBAR(); SCHED0();
    if (it + 2 < NT) {
      STAGE(cur, it + 2);
      asm volatile("s_waitcnt vmcnt(2)" ::: "memory");
    } else {
      asm volatile("s_waitcnt vmcnt(0)" ::: "memory");
    }
    SCHED0();
    SBAR(); SCHED0();
    cur ^= 1;
  }

#pragma unroll
  for (int i = 0; i < 4; ++i)
#pragma unroll
    for (int j = 0; j < 4; ++j)
#pragma unroll
      for (int rg = 0; rg < 4; ++rg) {
        int row = m0 + wm * 64 + i * 16 + lg * 4 + rg;
        int col = n0 + wn * 64 + j * 16 + lr;
        Op[((size_t)z * CH + row) * DT + col] = f2h(acc[i][j][rg]);
      }
}

// ---------------- l[r] = sum over vocab of E -----------------------------
__global__ __launch_bounds__(256) void k_lred(const float* __restrict__ lp,
                                              float* __restrict__ lv, int CH) {
  int rb = blockIdx.x * 256 + threadIdx.x;
  float s = 0.f;
  for (int nb = 0; nb < NB_N; ++nb) s += lp[(size_t)nb * CH + rb];
  lv[rb] = s;
}

// ------- combine split-K (f16 partials, int4 loads) + divide by l --------
__global__ __launch_bounds__(256) void k_out(const u16* __restrict__ Op,
                                             const float* __restrict__ lv,
                                             float* __restrict__ out,
                                             int row0, int CH) {
  int idx = blockIdx.x * 256 + threadIdx.x;
  int rb = idx >> 6, c8 = (idx & 63) * 8;
  float s[8] = {};
#pragma unroll
  for (int zz = 0; zz < KS; ++zz) {
    int4 vq = *(const int4*)&Op[((size_t)zz * CH + rb) * DT + c8];
    const f16* h = (const f16*)&vq;
#pragma unroll
    for (int k = 0; k < 8; ++k) s[k] += (float)h[k];
  }
  float inv = 1.0f / lv[rb];
  float4 o0 = {s[0] * inv, s[1] * inv, s[2] * inv, s[3] * inv};
  float4 o1 = {s[4] * inv, s[5] * inv, s[6] * inv, s[7] * inv};
  float* dst = &out[(size_t)(row0 + rb) * DT + c8];
  *(float4*)dst = o0;
  *(float4*)(dst + 4) = o1;
}

extern "C" void kernel_launch(void* const* d_in, const int* in_sizes, int n_in,
                              void* d_out, int out_size, void* d_ws, size_t ws_size,
                              hipStream_t stream) {
  const float* audio = (const float*)d_in[0];
  const float* W     = (const float*)d_in[1];
  const float* bias  = (const float*)d_in[2];
  const float* gamma = (const float*)d_in[3];
  const float* beta  = (const float*)d_in[4];
  const float* emb   = (const float*)d_in[5];
  float* out = (float*)d_out;

  char* ws = (char*)d_ws;
  size_t off = 0;
  auto alloc = [&](size_t bytes) {
    char* p = ws + off;
    off += (bytes + 255) & ~(size_t)255;
    return p;
  };
  float* proj   = (float*)alloc((size_t)MTOT * DT * 4);
  float* pstat  = (float*)alloc((size_t)2 * 16 * 512 * 4);
  float* stats  = (float*)alloc((size_t)2 * DT * 4);
  u16*   bnnH   = (u16*)alloc((size_t)MTOT * DT * 2);
  u16*   embH   = (u16*)alloc((size_t)NV * DT * 2);
  u16*   embT   = (u16*)alloc((size_t)DT * NV * 2);
  float* invn   = (float*)alloc((size_t)NV * 4);
  u16*   audioH = (u16*)alloc((size_t)MTOT * DA * 2);
  u16*   WT     = (u16*)alloc((size_t)DT * DA * 2);
  size_t fixed_off = off;

  int CH = 2048;
  while (CH > 256) {
    size_t need = fixed_off;
    need += (((size_t)CH * NV * 2) + 255) & ~(size_t)255;          // E
    need += (((size_t)NB_N * CH * 4) + 255) & ~(size_t)255;        // lpart
    need += (((size_t)CH * 4) + 255) & ~(size_t)255;               // lvec
    need += (((size_t)KS * CH * DT * 2) + 255) & ~(size_t)255;     // Op (f16)
    if (need <= ws_size) break;
    CH >>= 1;
  }
  u16*   E     = (u16*)alloc((size_t)CH * NV * 2);
  float* lpart = (float*)alloc((size_t)NB_N * CH * 4);
  float* lvec  = (float*)alloc((size_t)CH * 4);
  u16*   Op    = (u16*)alloc((size_t)KS * CH * DT * 2);
  if (ws_size < off) return;

  hipFuncSetAttribute((const void*)k_pv,
                      hipFuncAttributeMaxDynamicSharedMemorySize, 65536);

  k_prep<<<dim3(864), dim3(256), 0, stream>>>(audio, audioH, W, WT);
  k_proj<<<dim3(MTOT / 128, 2), dim3(512), 0, stream>>>(
      (const f16*)audioH, (const f16*)WT, bias, proj, pstat);
  k_stats2<<<dim3(2), dim3(256), 0, stream>>>(pstat, stats);
  k_bnnorm<<<dim3(MTOT), dim3(64), 0, stream>>>(proj, stats, gamma, beta, bnnH);
  k_embprep2<<<dim3(NV / 64), dim3(256), 0, stream>>>(emb, embH, embT, invn);

  for (int row0 = 0; row0 < MTOT; row0 += CH) {
    k_score<<<dim3(NB_N, CH / 128), dim3(512), 0, stream>>>(
        (const f16*)bnnH, (const f16*)embH, invn, E, lpart, row0, CH);
    k_lred<<<dim3(CH / 256), dim3(256), 0, stream>>>(lpart, lvec, CH);
    k_pv<<<dim3(2, CH >> 8, KS), dim3(1024), 65536, stream>>>(
        (const f16*)E, (const f16*)embT, Op, CH);
    k_out<<<dim3(CH / 4), dim3(256), 0, stream>>>(Op, lvec, out, row0, CH);
  }
}